// Round 9
// baseline (1662.214 us; speedup 1.0000x reference)
//
#include <hip/hip_runtime.h>
#include <hip/hip_cooperative_groups.h>
namespace cg = cooperative_groups;

#define BB 4
#define TT 12
#define NN 10000
#define DD 2
#define EE 320000
#define HH 64
#define NPREDD 12
#define TD 24
#define CHUNKS 250       // node chunks of 40
#define NPB 40           // nodes per chunk
#define NPW 5            // nodes per wave (8 waves * 5 = 40)
#define CAP 2048         // edges per chunk staged in LDS (mean 1280, max ~1450)

typedef __attribute__((ext_vector_type(8))) short bf16x8;
typedef __attribute__((ext_vector_type(4))) float f32x4;
typedef unsigned short u16;

__device__ __forceinline__ unsigned int pack2(float lo, float hi) {
    unsigned int r;
    asm("v_cvt_pk_bf16_f32 %0, %1, %2" : "=v"(r) : "v"(lo), "v"(hi));
    return r;
}
__device__ __forceinline__ float b2f(u16 u) {
    return __uint_as_float(((unsigned)u) << 16);
}

// ---------------- CSR build (keyed by dst; gather from src) ----------------
__global__ void hist_kernel(const int* __restrict__ dstv, int* __restrict__ deg) {
    int e = blockIdx.x*256 + threadIdx.x;
    if (e < EE) atomicAdd(&deg[dstv[e]], 1);
}

__global__ void scan_kernel(const int* __restrict__ deg, int* __restrict__ row_ptr,
                            int* __restrict__ cursor) {
    __shared__ int part[1024];
    int tid = threadIdx.x;
    const int CH = 10;
    int start = tid*CH;
    int s = 0;
    if (start < NN)
        for (int i=0;i<CH;i++) s += deg[start+i];
    part[tid] = s;
    __syncthreads();
    if (tid == 0) {
        int acc = 0;
        for (int i=0;i<1024;i++){ int v=part[i]; part[i]=acc; acc+=v; }
        row_ptr[NN] = acc;
    }
    __syncthreads();
    if (start < NN) {
        int acc = part[tid];
        for (int i=0;i<CH;i++){ int idx=start+i; row_ptr[idx]=acc; cursor[idx]=acc; acc+=deg[idx]; }
    }
}

__global__ void fill_kernel(const int* __restrict__ srcv, const int* __restrict__ dstv,
                            const float* __restrict__ ew, int* __restrict__ cursor,
                            int2* __restrict__ csr) {
    int e = blockIdx.x*256 + threadIdx.x;
    if (e < EE) {
        int d = dstv[e];
        int pos = atomicAdd(&cursor[d], 1);
        csr[pos] = make_int2(srcv[e], __float_as_int(ew[e]));
    }
}

// ---------------- x transpose: [B,T,N,D] -> [N][T*D][B] ----------------
__global__ void transpose_x(const float* __restrict__ x, float* __restrict__ xTb) {
    int idx = blockIdx.x*256 + threadIdx.x;
    if (idx >= BB*TT*NN*DD) return;
    int d = idx & 1;
    int n = (idx >> 1) % NN;
    int t = (idx / (NN*DD)) % TT;
    int b = idx / (TT*NN*DD);
    xTb[((size_t)n*TD + (t*DD + d))*BB + b] = x[idx];
}

// ---------------- AX = A @ x_t for all t,b; layout [N][TD][B] ----------------
__global__ __launch_bounds__(256)
void ax_gather(const float* __restrict__ xTb, const int* __restrict__ row_ptr,
               const int2* __restrict__ csr, float* __restrict__ AXb) {
    int gw = (blockIdx.x*256 + threadIdx.x) >> 6;
    if (gw >= NN) return;
    int n = gw;
    int lane = threadIdx.x & 63;
    int half = lane >> 5;
    int c = lane & 31;
    float4 acc = {0.f,0.f,0.f,0.f};
    int e0 = row_ptr[n], e1 = row_ptr[n+1];
    for (int e = e0; e < e1; e += 8) {
        int ia = e + half, ib = e + 2 + half, ic = e + 4 + half, id = e + 6 + half;
        int2 ca = csr[ia]; int2 cb = csr[ib]; int2 cc = csr[ic]; int2 cd = csr[id];
        float wa = (ia < e1) ? __int_as_float(ca.y) : 0.f;
        float wb = (ib < e1) ? __int_as_float(cb.y) : 0.f;
        float wc = (ic < e1) ? __int_as_float(cc.y) : 0.f;
        float wd = (id < e1) ? __int_as_float(cd.y) : 0.f;
        const float4 va = *(const float4*)(xTb + (size_t)ca.x*(TD*BB) + c*4);
        const float4 vb = *(const float4*)(xTb + (size_t)cb.x*(TD*BB) + c*4);
        const float4 vc = *(const float4*)(xTb + (size_t)cc.x*(TD*BB) + c*4);
        const float4 vd = *(const float4*)(xTb + (size_t)cd.x*(TD*BB) + c*4);
        acc.x = fmaf(wa, va.x, acc.x); acc.y = fmaf(wa, va.y, acc.y);
        acc.z = fmaf(wa, va.z, acc.z); acc.w = fmaf(wa, va.w, acc.w);
        acc.x = fmaf(wb, vb.x, acc.x); acc.y = fmaf(wb, vb.y, acc.y);
        acc.z = fmaf(wb, vb.z, acc.z); acc.w = fmaf(wb, vb.w, acc.w);
        acc.x = fmaf(wc, vc.x, acc.x); acc.y = fmaf(wc, vc.y, acc.y);
        acc.z = fmaf(wc, vc.z, acc.z); acc.w = fmaf(wc, vc.w, acc.w);
        acc.x = fmaf(wd, vd.x, acc.x); acc.y = fmaf(wd, vd.y, acc.y);
        acc.z = fmaf(wd, vd.z, acc.z); acc.w = fmaf(wd, vd.w, acc.w);
    }
    acc.x += __shfl_xor(acc.x, 32); acc.y += __shfl_xor(acc.y, 32);
    acc.z += __shfl_xor(acc.z, 32); acc.w += __shfl_xor(acc.w, 32);
    if (lane < TD) *(float4*)(AXb + (size_t)n*(TD*BB) + lane*4) = acc;
}

// ---------------- weight fragments in MFMA B-operand order ----------------
__global__ void prep_wfrag(const float* __restrict__ W0, const float* __restrict__ W1,
                           unsigned short* __restrict__ wf0, unsigned short* __restrict__ wf1) {
    int tid = blockIdx.x*256 + threadIdx.x;
    if (tid >= 2560) return;
    int layer = tid / 1280;
    int r = tid % 1280;
    int lane = r & 63;
    int ctkt = r >> 6;
    int ct = ctkt / 5, kt = ctkt % 5;
    int c = ct*16 + (lane & 15);
    int k0 = kt*32 + (lane >> 4)*8;
    unsigned short* dst = (layer ? wf1 : wf0) + r*8;
    for (int j=0;j<8;j++) {
        int k = k0 + j;
        float w = 0.f;
        if (layer == 0) {
            if (k < 64)        w = W0[(2+k)*64 + c];
            else if (k < 128)  w = W0[4224 + (2+(k-64))*64 + c];
            else if (k == 128) w = W0[c];
            else if (k == 129) w = W0[64 + c];
            else if (k == 130) w = W0[4224 + c];
            else if (k == 131) w = W0[4224 + 64 + c];
        } else {
            if (k < 64)        w = W1[k*64 + c] + W1[(k+64)*64 + c];
            else if (k < 128)  w = W1[8192 + (k-64)*64 + c] + W1[8192 + k*64 + c];
        }
        unsigned int u = __float_as_uint(w);
        unsigned int rnd = (u + 0x7fffu + ((u >> 16) & 1u)) >> 16;   // RNE
        dst[j] = (unsigned short)rnd;
    }
}

// ---------------- persistent cooperative kernel: all 24 layer phases + output ----------------
// 512 thr = 8 waves. Block handles 1-2 chunks (40 nodes each) x one batch-pair p=bid&1.
// LDS: predecoded edges (byte_off, w) staged ONCE, reused 24 phases.
// lane: eh=lane>>5 (edge parity), laneB=(lane>>4)&1 (batch in pair), cq=lane&15 (ch quad).
__global__ __launch_bounds__(512, 4)
void persist_kernel(u16* __restrict__ hA, u16* __restrict__ hB,
                    const float* __restrict__ x, const float* __restrict__ AXb,
                    const unsigned short* __restrict__ wf0, const unsigned short* __restrict__ wf1,
                    const float* __restrict__ b0, const float* __restrict__ b1,
                    const int* __restrict__ row_ptr, const int2* __restrict__ csr,
                    const float* __restrict__ Wp, const float* __restrict__ bp,
                    float* __restrict__ outp)
{
    __shared__ int2 sIdx[2][CAP];             // 32 KB predecoded edges
    __shared__ unsigned short sA[NPB*2*168];  // 26.9 KB: 80-row bf16 A tile

    cg::grid_group gg = cg::this_grid();

    const int tid = threadIdx.x;
    const int wave = tid >> 6, lane = tid & 63;
    const int eh = lane >> 5, laneB = (lane >> 4) & 1, cq = lane & 15;
    const int G = (int)gridDim.x;
    const int bid = (int)blockIdx.x;
    const int p = bid & 1;
    const int ck0 = bid >> 1;
    const int ck1 = ck0 + (G >> 1);
    const int nck = (ck1 < CHUNKS) ? 2 : 1;
    const int laneoff = ((p*2 + laneB)*HH + cq*4) * 2;   // bytes within 512B node row

    // ---- P0: predecode this block's csr segments into LDS (once) ----
    for (int s = 0; s < nck; ++s) {
        int ck = (s == 0) ? ck0 : ck1;
        int estart = row_ptr[ck*NPB];
        int cnt = row_ptr[ck*NPB + NPB] - estart;
        if (cnt > CAP) cnt = CAP;
        for (int i = tid; i < CAP; i += 512) {
            int2 v = make_int2(0, 0);
            if (i < cnt) { int2 cw = csr[estart + i]; v = make_int2(cw.x << 9, cw.y); }
            sIdx[s][i] = v;
        }
    }
    __syncthreads();

    // ---- 12 timesteps x 2 layers ----
    for (int t = 0; t < TT; ++t) {
        for (int half = 0; half < 2; ++half) {
            const int L0 = (half == 0);
            const u16* hin = L0 ? hA : hB;
            u16* hout = L0 ? hB : hA;
            const unsigned short* wf = L0 ? wf0 : wf1;
            const float* bias = L0 ? b0 : b1;

            for (int s = 0; s < nck; ++s) {
                int ck = (s == 0) ? ck0 : ck1;
                int estart = row_ptr[ck*NPB];
                int cntL = row_ptr[ck*NPB + NPB] - estart;
                if (cntL > CAP) cntL = CAP;

                for (int j = 0; j < NPW; ++j) {
                    int n = ck*NPB + wave*NPW + j;
                    int rowL = (wave*NPW + j)*2 + laneB;

                    if (L0 && t == 0) {
                        // h == 0: zero the h and A@h regions
                        if (eh == 0) {
                            *(uint2*)&sA[rowL*168 + cq*4] = make_uint2(0u,0u);
                            *(uint2*)&sA[rowL*168 + 64 + cq*4] = make_uint2(0u,0u);
                        }
                    } else {
                        int eb = row_ptr[n] - estart;
                        int ee = row_ptr[n+1] - estart;
                        ushort4 hv = make_ushort4(0,0,0,0);
                        if (eh == 0)
                            hv = *(const ushort4*)((const char*)hin + ((size_t)n << 9) + laneoff);
                        float4 acc = {0.f,0.f,0.f,0.f};
                        int tmax = (ee - eb + 31) >> 5;
                        if (ee <= cntL) {
                            for (int tt = 0; tt < tmax; ++tt) {
                                int base = eb + (tt<<5) + eh;
                                #pragma unroll
                                for (int u = 0; u < 16; ++u) {
                                    int idx = base + 2*u;
                                    int2 ow = sIdx[s][idx & (CAP-1)];
                                    float w = (idx < ee) ? __int_as_float(ow.y) : 0.f;
                                    ushort4 v = *(const ushort4*)((const char*)hin + ow.x + laneoff);
                                    acc.x = fmaf(w, b2f(v.x), acc.x);
                                    acc.y = fmaf(w, b2f(v.y), acc.y);
                                    acc.z = fmaf(w, b2f(v.z), acc.z);
                                    acc.w = fmaf(w, b2f(v.w), acc.w);
                                }
                            }
                        } else {
                            for (int tt = 0; tt < tmax; ++tt) {
                                int base = eb + (tt<<5) + eh;
                                #pragma unroll
                                for (int u = 0; u < 16; ++u) {
                                    int idx = base + 2*u;
                                    int2 cw = (idx < ee) ? csr[estart + idx] : make_int2(0,0);
                                    float w = (idx < ee) ? __int_as_float(cw.y) : 0.f;
                                    ushort4 v = *(const ushort4*)((const char*)hin + ((size_t)cw.x << 9) + laneoff);
                                    acc.x = fmaf(w, b2f(v.x), acc.x);
                                    acc.y = fmaf(w, b2f(v.y), acc.y);
                                    acc.z = fmaf(w, b2f(v.z), acc.z);
                                    acc.w = fmaf(w, b2f(v.w), acc.w);
                                }
                            }
                        }
                        acc.x += __shfl_xor(acc.x, 32); acc.y += __shfl_xor(acc.y, 32);
                        acc.z += __shfl_xor(acc.z, 32); acc.w += __shfl_xor(acc.w, 32);
                        if (eh == 0) {
                            *(ushort4*)&sA[rowL*168 + cq*4] = hv;
                            uint2 pk; pk.x = pack2(acc.x, acc.y); pk.y = pack2(acc.z, acc.w);
                            *(uint2*)&sA[rowL*168 + 64 + cq*4] = pk;
                        }
                    }
                    // extras (k=128..131) + zero tail (k=132..159), eh==1 lanes
                    if (eh == 1) {
                        if (cq == 0) {
                            uint2 pk;
                            if (L0) {
                                int b = p*2 + laneB;
                                const float2 xv = *(const float2*)(x + (((size_t)b*TT + t)*NN + n)*DD);
                                float ax0 = AXb[(size_t)n*(TD*BB) + (2*t)*BB + b];
                                float ax1 = AXb[(size_t)n*(TD*BB) + (2*t+1)*BB + b];
                                pk.x = pack2(xv.x, xv.y); pk.y = pack2(ax0, ax1);
                            } else { pk.x = 0u; pk.y = 0u; }
                            *(uint2*)&sA[rowL*168 + 128] = pk;
                        } else if (cq < 8) {
                            *(uint2*)&sA[rowL*168 + 132 + (cq-1)*4] = make_uint2(0u,0u);
                        }
                    }
                }
                __syncthreads();

                // MFMA: 20 C-tiles (5 M x 4 N) over K=160
                const bf16x8* wfv = (const bf16x8*)wf;
                for (int tile = wave; tile < 20; tile += 8) {
                    int mt = tile >> 2, ct = tile & 3;
                    f32x4 dacc = {0.f,0.f,0.f,0.f};
                    #pragma unroll
                    for (int kt = 0; kt < 5; ++kt) {
                        bf16x8 bfr = wfv[(ct*5 + kt)*64 + lane];
                        bf16x8 a = *(const bf16x8*)&sA[(mt*16 + cq)*168 + kt*32 + (lane>>4)*8];
                        dacc = __builtin_amdgcn_mfma_f32_16x16x32_bf16(a, bfr, dacc, 0, 0, 0);
                    }
                    float bv = bias[ct*16 + cq];
                    #pragma unroll
                    for (int i2 = 0; i2 < 4; ++i2) {
                        int r = mt*16 + (lane>>4)*4 + i2;
                        int n = ck*NPB + (r >> 1);
                        int b = p*2 + (r & 1);
                        float vv = fmaxf(dacc[i2] + bv, 0.f);
                        unsigned pk = pack2(vv, vv);
                        __builtin_nontemporal_store((u16)pk,
                            hout + ((size_t)n*BB + b)*HH + ct*16 + cq);
                    }
                }
                __syncthreads();
            } // chunks
            if (!(t == TT-1 && half == 1)) gg.sync();
        } // half
    } // t

    // ---- output: own rows, no sync needed (we wrote them) ----
    for (int s = 0; s < nck; ++s) {
        int ck = (s == 0) ? ck0 : ck1;
        for (int r = wave; r < NPB*2; r += 8) {
            int n = ck*NPB + (r >> 1);
            int b = p*2 + (r & 1);
            float v = b2f(hA[((size_t)n*BB + b)*HH + lane]) * Wp[lane];
            for (int off = 32; off; off >>= 1) v += __shfl_down(v, off);
            v = __shfl(v, 0) + bp[0];
            if (lane < NPREDD) outp[((size_t)b*NPREDD + lane)*NN + n] = v;
        }
    }
}

extern "C" void kernel_launch(void* const* d_in, const int* in_sizes, int n_in,
                              void* d_out, int out_size, void* d_ws, size_t ws_size,
                              hipStream_t stream) {
    const float* x   = (const float*)d_in[0];
    const int*   ei  = (const int*)d_in[1];
    const float* ew  = (const float*)d_in[2];
    const float* W0  = (const float*)d_in[3];
    const float* b0  = (const float*)d_in[4];
    const float* W1  = (const float*)d_in[5];
    const float* b1  = (const float*)d_in[6];
    const float* Wp  = (const float*)d_in[7];
    const float* bp  = (const float*)d_in[8];
    float* outp = (float*)d_out;

    char* ws = (char*)d_ws;
    size_t off = 0;
    auto alloc = [&](size_t bytes) { void* p = ws + off; off = (off + bytes + 255) & ~(size_t)255; return p; };
    u16* h      = (u16*)alloc((size_t)NN*BB*HH*2);
    u16* h1     = (u16*)alloc((size_t)NN*BB*HH*2);
    float* xTb  = (float*)alloc(((size_t)NN*TD*BB + 64)*4);
    float* AXb  = (float*)alloc((size_t)NN*TD*BB*4);
    unsigned short* wf0 = (unsigned short*)alloc(1280*8*2);
    unsigned short* wf1 = (unsigned short*)alloc(1280*8*2);
    int2*  csr  = (int2*)alloc(((size_t)EE + 16)*8);
    int* row_ptr= (int*)alloc((NN+1)*4);
    int* deg    = (int*)alloc(NN*4);
    int* cursor = (int*)alloc(NN*4);

    const int* srcv = ei;
    const int* dstv = ei + EE;

    hipMemsetAsync(deg, 0, NN*4, stream);
    hipMemsetAsync(h, 0, (size_t)NN*BB*HH*2, stream);
    hipMemsetAsync(csr + EE, 0, 16*8, stream);

    hist_kernel<<<(EE+255)/256, 256, 0, stream>>>(dstv, deg);
    scan_kernel<<<1, 1024, 0, stream>>>(deg, row_ptr, cursor);
    fill_kernel<<<(EE+255)/256, 256, 0, stream>>>(srcv, dstv, ew, cursor, csr);
    transpose_x<<<(BB*TT*NN*DD+255)/256, 256, 0, stream>>>(x, xTb);
    ax_gather<<<(NN*64+255)/256, 256, 0, stream>>>(xTb, row_ptr, csr, AXb);
    prep_wfrag<<<10, 256, 0, stream>>>(W0, W1, wf0, wf1);

    // grid size: 2 blocks/CU if they fit, else 1 (kernel handles 1-2 chunks/block)
    int occ = 0;
    hipOccupancyMaxActiveBlocksPerMultiprocessor(&occ, persist_kernel, 512, 0);
    int Gr = (occ >= 2) ? 2*CHUNKS : CHUNKS;

    void* kargs[] = { (void*)&h, (void*)&h1, (void*)&x, (void*)&AXb,
                      (void*)&wf0, (void*)&wf1, (void*)&b0, (void*)&b1,
                      (void*)&row_ptr, (void*)&csr, (void*)&Wp, (void*)&bp, (void*)&outp };
    hipLaunchCooperativeKernel((void*)persist_kernel, dim3(Gr), dim3(512), kargs, 0, stream);
}

// Round 10
// 708.122 us; speedup vs baseline: 2.3474x; 2.3474x over previous
//
#include <hip/hip_runtime.h>

#define BB 4
#define TT 12
#define NN 10000
#define DD 2
#define EE 320000
#define HH 64
#define NPREDD 12
#define TD 24
#define CAP2 1024        // edges per 16-node chunk staged in LDS (mean 512, max ~700)

typedef __attribute__((ext_vector_type(8))) short bf16x8;
typedef __attribute__((ext_vector_type(4))) float f32x4;
typedef unsigned short u16;

__device__ __forceinline__ unsigned int pack2(float lo, float hi) {
    unsigned int r;
    asm("v_cvt_pk_bf16_f32 %0, %1, %2" : "=v"(r) : "v"(lo), "v"(hi));
    return r;
}
__device__ __forceinline__ float b2f(u16 u) {
    return __uint_as_float(((unsigned)u) << 16);
}

// ---------------- CSR build (keyed by dst; gather from src) ----------------
__global__ void hist_kernel(const int* __restrict__ dstv, int* __restrict__ deg) {
    int e = blockIdx.x*256 + threadIdx.x;
    if (e < EE) atomicAdd(&deg[dstv[e]], 1);
}

__global__ void scan_kernel(const int* __restrict__ deg, int* __restrict__ row_ptr,
                            int* __restrict__ cursor) {
    __shared__ int part[1024];
    int tid = threadIdx.x;
    const int CH = 10;
    int start = tid*CH;
    int s = 0;
    if (start < NN)
        for (int i=0;i<CH;i++) s += deg[start+i];
    part[tid] = s;
    __syncthreads();
    if (tid == 0) {
        int acc = 0;
        for (int i=0;i<1024;i++){ int v=part[i]; part[i]=acc; acc+=v; }
        row_ptr[NN] = acc;
    }
    __syncthreads();
    if (start < NN) {
        int acc = part[tid];
        for (int i=0;i<CH;i++){ int idx=start+i; row_ptr[idx]=acc; cursor[idx]=acc; acc+=deg[idx]; }
    }
}

__global__ void fill_kernel(const int* __restrict__ srcv, const int* __restrict__ dstv,
                            const float* __restrict__ ew, int* __restrict__ cursor,
                            int2* __restrict__ csr) {
    int e = blockIdx.x*256 + threadIdx.x;
    if (e < EE) {
        int d = dstv[e];
        int pos = atomicAdd(&cursor[d], 1);
        csr[pos] = make_int2(srcv[e], __float_as_int(ew[e]));
    }
}

// ---------------- x transpose: [B,T,N,D] -> [N][T*D][B] (batch fastest) ----------------
__global__ void transpose_x(const float* __restrict__ x, float* __restrict__ xTb) {
    int idx = blockIdx.x*256 + threadIdx.x;
    if (idx >= BB*TT*NN*DD) return;
    int d = idx & 1;
    int n = (idx >> 1) % NN;
    int t = (idx / (NN*DD)) % TT;
    int b = idx / (TT*NN*DD);
    xTb[((size_t)n*TD + (t*DD + d))*BB + b] = x[idx];
}

// ---------------- AX = A @ x_t for all t,b at once; layout [N][TD][B] ----------------
__global__ __launch_bounds__(256)
void ax_gather(const float* __restrict__ xTb, const int* __restrict__ row_ptr,
               const int2* __restrict__ csr, float* __restrict__ AXb) {
    int gw = (blockIdx.x*256 + threadIdx.x) >> 6;
    if (gw >= NN) return;
    int n = gw;
    int lane = threadIdx.x & 63;
    int half = lane >> 5;
    int c = lane & 31;
    float4 acc = {0.f,0.f,0.f,0.f};
    int e0 = row_ptr[n], e1 = row_ptr[n+1];
    for (int e = e0; e < e1; e += 8) {
        int ia = e + half, ib = e + 2 + half, ic = e + 4 + half, id = e + 6 + half;
        int2 ca = csr[ia]; int2 cb = csr[ib]; int2 cc = csr[ic]; int2 cd = csr[id];
        float wa = (ia < e1) ? __int_as_float(ca.y) : 0.f;
        float wb = (ib < e1) ? __int_as_float(cb.y) : 0.f;
        float wc = (ic < e1) ? __int_as_float(cc.y) : 0.f;
        float wd = (id < e1) ? __int_as_float(cd.y) : 0.f;
        const float4 va = *(const float4*)(xTb + (size_t)ca.x*(TD*BB) + c*4);
        const float4 vb = *(const float4*)(xTb + (size_t)cb.x*(TD*BB) + c*4);
        const float4 vc = *(const float4*)(xTb + (size_t)cc.x*(TD*BB) + c*4);
        const float4 vd = *(const float4*)(xTb + (size_t)cd.x*(TD*BB) + c*4);
        acc.x = fmaf(wa, va.x, acc.x); acc.y = fmaf(wa, va.y, acc.y);
        acc.z = fmaf(wa, va.z, acc.z); acc.w = fmaf(wa, va.w, acc.w);
        acc.x = fmaf(wb, vb.x, acc.x); acc.y = fmaf(wb, vb.y, acc.y);
        acc.z = fmaf(wb, vb.z, acc.z); acc.w = fmaf(wb, vb.w, acc.w);
        acc.x = fmaf(wc, vc.x, acc.x); acc.y = fmaf(wc, vc.y, acc.y);
        acc.z = fmaf(wc, vc.z, acc.z); acc.w = fmaf(wc, vc.w, acc.w);
        acc.x = fmaf(wd, vd.x, acc.x); acc.y = fmaf(wd, vd.y, acc.y);
        acc.z = fmaf(wd, vd.z, acc.z); acc.w = fmaf(wd, vd.w, acc.w);
    }
    acc.x += __shfl_xor(acc.x, 32); acc.y += __shfl_xor(acc.y, 32);
    acc.z += __shfl_xor(acc.z, 32); acc.w += __shfl_xor(acc.w, 32);
    if (lane < TD) *(float4*)(AXb + (size_t)n*(TD*BB) + lane*4) = acc;
}

// ---------------- weight fragments in MFMA B-operand order ----------------
__global__ void prep_wfrag(const float* __restrict__ W0, const float* __restrict__ W1,
                           unsigned short* __restrict__ wf0, unsigned short* __restrict__ wf1) {
    int tid = blockIdx.x*256 + threadIdx.x;
    if (tid >= 2560) return;
    int layer = tid / 1280;
    int r = tid % 1280;
    int lane = r & 63;
    int ctkt = r >> 6;
    int ct = ctkt / 5, kt = ctkt % 5;
    int c = ct*16 + (lane & 15);
    int k0 = kt*32 + (lane >> 4)*8;
    unsigned short* dst = (layer ? wf1 : wf0) + r*8;
    for (int j=0;j<8;j++) {
        int k = k0 + j;
        float w = 0.f;
        if (layer == 0) {
            if (k < 64)        w = W0[(2+k)*64 + c];
            else if (k < 128)  w = W0[4224 + (2+(k-64))*64 + c];
            else if (k == 128) w = W0[c];
            else if (k == 129) w = W0[64 + c];
            else if (k == 130) w = W0[4224 + c];
            else if (k == 131) w = W0[4224 + 64 + c];
        } else {
            if (k < 64)        w = W1[k*64 + c] + W1[(k+64)*64 + c];
            else if (k < 128)  w = W1[8192 + (k-64)*64 + c] + W1[8192 + k*64 + c];
        }
        unsigned int u = __float_as_uint(w);
        unsigned int rnd = (u + 0x7fffu + ((u >> 16) & 1u)) >> 16;   // RNE
        dst[j] = (unsigned short)rnd;
    }
}

// ---------------- fused layer, batch-PAIR split ----------------
// h layout: [N][B][64] bf16 (node row = 512 B).
// Block: pair = bid&1 (batches 2p,2p+1), chunk = bid>>1 (16 nodes).
// Even bids -> even XCDs (round-robin), so each XCD touches one pair's h
// (2.56 MB) -> L2-resident gather.
// Wave: 2 nodes; lane: nsel=lane>>5 (node), laneB=(lane>>4)&1 (batch in pair),
// cq=lane&15 (ch quad). One edge = one 256B half-wave coalesced load.
// MFMA: 32 rows = 16 nodes x 2 batches, K=160, N=64; 8 C-tiles, 1/wave.
template<int L0, int Z>
__global__ __launch_bounds__(512)
void layer_kernel(const u16* __restrict__ h_in,
                  const float* __restrict__ x,
                  const float* __restrict__ AXb,
                  const unsigned short* __restrict__ wf,
                  const float* __restrict__ bias,
                  const int* __restrict__ row_ptr,
                  const int2* __restrict__ csr,
                  u16* __restrict__ h_out,
                  int t)
{
    __shared__ int2 sIdx[CAP2];             // 8 KB: predecoded (byte_off, w)
    __shared__ unsigned short sA[32*168];   // 10.5 KB: bf16 MFMA A tile

    int tid = threadIdx.x;
    int wave = tid >> 6, lane = tid & 63;
    int nsel = lane >> 5, laneB = (lane >> 4) & 1, cq = lane & 15;

    int pair = blockIdx.x & 1;
    int chunk = blockIdx.x >> 1;            // 0..624
    int n0 = chunk * 16;
    int b = pair*2 + laneB;
    int laneoff = (b*HH + cq*4)*2;          // byte offset within 512B node row

    int estart = 0, cnt = 0;
    if (!Z) {
        estart = row_ptr[n0];
        cnt = row_ptr[n0 + 16] - estart;
        int lim = cnt > CAP2 ? CAP2 : cnt;
        for (int i = tid; i < CAP2; i += 512) {
            int2 v = make_int2(0, 0);
            if (i < lim) { int2 cw = csr[estart + i]; v = make_int2(cw.x << 9, cw.y); }
            sIdx[i] = v;
        }
    }

    // wave's B fragments + bias
    int ct = wave & 3, mt = wave >> 2;
    const bf16x8* wfv = (const bf16x8*)wf;
    bf16x8 bfr[5];
    #pragma unroll
    for (int kt=0; kt<5; ++kt) bfr[kt] = wfv[(ct*5+kt)*64 + lane];
    float bv = bias[ct*16 + cq];

    int n = n0 + wave*2 + nsel;
    int rowL = (wave*2 + nsel)*2 + laneB;

    ushort4 hv = make_ushort4(0,0,0,0);
    float4 acc = {0.f,0.f,0.f,0.f};
    if (!Z) {
        int eb = row_ptr[n] - estart;
        int ee = row_ptr[n+1] - estart;
        hv = *(const ushort4*)((const char*)h_in + ((size_t)n << 9) + laneoff);
        __syncthreads();                    // sIdx staged
        if (cnt <= CAP2) {
            for (int e = eb; e < ee; e += 8) {
                #pragma unroll
                for (int u = 0; u < 8; ++u) {
                    int idx = e + u;
                    int2 ow = sIdx[idx & (CAP2-1)];
                    float w = (idx < ee) ? __int_as_float(ow.y) : 0.f;
                    ushort4 v = *(const ushort4*)((const char*)h_in + ow.x + laneoff);
                    acc.x = fmaf(w, b2f(v.x), acc.x);
                    acc.y = fmaf(w, b2f(v.y), acc.y);
                    acc.z = fmaf(w, b2f(v.z), acc.z);
                    acc.w = fmaf(w, b2f(v.w), acc.w);
                }
            }
        } else {
            // fallback: chunk segment overflowed CAP2 (practically unreachable)
            for (int e = eb; e < ee; e += 8) {
                #pragma unroll
                for (int u = 0; u < 8; ++u) {
                    int idx = e + u;
                    int2 cw = (idx < ee) ? csr[estart + idx] : make_int2(0,0);
                    float w = (idx < ee) ? __int_as_float(cw.y) : 0.f;
                    ushort4 v = *(const ushort4*)((const char*)h_in + ((size_t)cw.x << 9) + laneoff);
                    acc.x = fmaf(w, b2f(v.x), acc.x);
                    acc.y = fmaf(w, b2f(v.y), acc.y);
                    acc.z = fmaf(w, b2f(v.z), acc.z);
                    acc.w = fmaf(w, b2f(v.w), acc.w);
                }
            }
        }
    }

    // stage A tile row
    *(ushort4*)&sA[rowL*168 + cq*4] = hv;
    { uint2 pk; pk.x = pack2(acc.x, acc.y); pk.y = pack2(acc.z, acc.w);
      *(uint2*)&sA[rowL*168 + 64 + cq*4] = pk; }
    if (cq == 0) {
        uint2 pk;
        if (L0) {
            const float2 xv = *(const float2*)(x + (((size_t)b*TT + t)*NN + n)*DD);
            float ax0 = AXb[(size_t)n*(TD*BB) + (2*t)*BB + b];
            float ax1 = AXb[(size_t)n*(TD*BB) + (2*t+1)*BB + b];
            pk.x = pack2(xv.x, xv.y); pk.y = pack2(ax0, ax1);
        } else { pk.x = 0u; pk.y = 0u; }
        *(uint2*)&sA[rowL*168 + 128] = pk;
    } else if (cq < 8) {
        *(uint2*)&sA[rowL*168 + 132 + (cq-1)*4] = make_uint2(0u, 0u);
    }
    __syncthreads();

    // MFMA: C-tile (mt, ct); A row = lane&15, k = (lane>>4)*8 + j
    f32x4 dacc = {0.f,0.f,0.f,0.f};
    #pragma unroll
    for (int kt=0; kt<5; ++kt) {
        bf16x8 a = *(const bf16x8*)&sA[(mt*16 + cq)*168 + kt*32 + (lane>>4)*8];
        dacc = __builtin_amdgcn_mfma_f32_16x16x32_bf16(a, bfr[kt], dacc, 0, 0, 0);
    }
    #pragma unroll
    for (int i2=0;i2<4;i2++) {
        int r = mt*16 + (lane>>4)*4 + i2;    // C/D: row=(lane>>4)*4+reg, col=lane&15
        int nodeL = r >> 1, bo = pair*2 + (r & 1);
        float vv = fmaxf(dacc[i2] + bv, 0.f);
        unsigned pk = pack2(vv, vv);
        h_out[((size_t)(n0 + nodeL)*BB + bo)*HH + ct*16 + cq] = (u16)pk;
    }
}

// ---------------- output ----------------
__global__ void out_kernel(const u16* __restrict__ h, const float* __restrict__ Wp,
                           const float* __restrict__ bp, float* __restrict__ outp) {
    int g = blockIdx.x*256 + threadIdx.x;
    int wave = g >> 6, lane = g & 63;
    if (wave >= BB*NN) return;
    int b = wave / NN, n = wave - b*NN;
    float v = b2f(h[((size_t)n*BB + b)*HH + lane]) * Wp[lane];
    for (int off=32; off; off>>=1) v += __shfl_down(v, off);
    v = __shfl(v, 0) + bp[0];
    if (lane < NPREDD) outp[((size_t)b*NPREDD + lane)*NN + n] = v;
}

extern "C" void kernel_launch(void* const* d_in, const int* in_sizes, int n_in,
                              void* d_out, int out_size, void* d_ws, size_t ws_size,
                              hipStream_t stream) {
    const float* x   = (const float*)d_in[0];
    const int*   ei  = (const int*)d_in[1];
    const float* ew  = (const float*)d_in[2];
    const float* W0  = (const float*)d_in[3];
    const float* b0  = (const float*)d_in[4];
    const float* W1  = (const float*)d_in[5];
    const float* b1  = (const float*)d_in[6];
    const float* Wp  = (const float*)d_in[7];
    const float* bp  = (const float*)d_in[8];
    float* outp = (float*)d_out;

    char* ws = (char*)d_ws;
    size_t off = 0;
    auto alloc = [&](size_t bytes) { void* p = ws + off; off = (off + bytes + 255) & ~(size_t)255; return p; };
    u16* h      = (u16*)alloc((size_t)NN*BB*HH*2);
    u16* h1     = (u16*)alloc((size_t)NN*BB*HH*2);
    float* xTb  = (float*)alloc(((size_t)NN*TD*BB + 64)*4);
    float* AXb  = (float*)alloc((size_t)NN*TD*BB*4);
    unsigned short* wf0 = (unsigned short*)alloc(1280*8*2);
    unsigned short* wf1 = (unsigned short*)alloc(1280*8*2);
    int2*  csr  = (int2*)alloc(((size_t)EE + 16)*8);
    int* row_ptr= (int*)alloc((NN+1)*4);
    int* deg    = (int*)alloc(NN*4);
    int* cursor = (int*)alloc(NN*4);

    const int* srcv = ei;
    const int* dstv = ei + EE;

    hipMemsetAsync(deg, 0, NN*4, stream);
    hipMemsetAsync(csr + EE, 0, 16*8, stream);

    hist_kernel<<<(EE+255)/256, 256, 0, stream>>>(dstv, deg);
    scan_kernel<<<1, 1024, 0, stream>>>(deg, row_ptr, cursor);
    fill_kernel<<<(EE+255)/256, 256, 0, stream>>>(srcv, dstv, ew, cursor, csr);
    transpose_x<<<(BB*TT*NN*DD+255)/256, 256, 0, stream>>>(x, xTb);
    ax_gather<<<(NN*64+255)/256, 256, 0, stream>>>(xTb, row_ptr, csr, AXb);
    prep_wfrag<<<10, 256, 0, stream>>>(W0, W1, wf0, wf1);

    const int grid = 1250;   // 625 chunks x 2 batch-pairs
    // t = 0: layer0 has h==0 -> Z variant (no gather, no h read)
    layer_kernel<1,1><<<grid, 512, 0, stream>>>(h,  x, AXb, wf0, b0, row_ptr, csr, h1, 0);
    layer_kernel<0,0><<<grid, 512, 0, stream>>>(h1, nullptr, nullptr, wf1, b1, row_ptr, csr, h, 0);
    for (int t=1; t<TT; ++t) {
        layer_kernel<1,0><<<grid, 512, 0, stream>>>(h,  x, AXb, wf0, b0, row_ptr, csr, h1, t);
        layer_kernel<0,0><<<grid, 512, 0, stream>>>(h1, nullptr, nullptr, wf1, b1, row_ptr, csr, h, 0);
    }
    out_kernel<<<(BB*NN*64+255)/256, 256, 0, stream>>>(h, Wp, bp, outp);
}